// Round 11
// baseline (195.862 us; speedup 1.0000x reference)
//
#include <hip/hip_runtime.h>

typedef unsigned long long ull;

#define HH 256
#define WW 256
#define PLANE (HH*WW)
#define TILE_R 32
#define TILE_C 64
#define TT 16
#define ER (TILE_R + 2*TT)   // 64 ext rows
#define EC (TILE_C + 2*TT)   // 96 ext cols -> 48 uv-pairs per row
#define NCP (EC/2)           // 48 col-pairs per row
#define NRG 8                // row groups
#define RPT (ER/NRG)         // 8 rows per thread
#define NTHR 384             // = NCP*NRG, zero idle threads (6 waves)
#define RS 192               // floats per LDS row (48 pairs x 4)
#define LBUF (4 + ER*RS + 4) // 12296 floats = 49184 B per buffer
#define SMEM_BYTES (2*LBUF*4)

#define RING_OFS (2u*1024u*1024u)   // float offset of ring slot 1 (8 MB)
#define FLAG_OFS (4u*1024u*1024u)   // float offset of flag array (16 MB)
#define RIMG (HH*(WW/2)*4)          // floats per interleaved ring image (131072)
#define NBLK 256

// one Jacobi step over this thread's 2 cols x 8 rows; own-row centers carried in Mreg
__device__ __forceinline__ void hs_step(
    const float* __restrict__ rbuf, float* __restrict__ wbuf,
    int fb, int rm, int r0, int rN,
    float4* __restrict__ Mreg,
    const float2* __restrict__ ca, const float2* __restrict__ cb,
    const float2* __restrict__ cc, const float2* __restrict__ cd,
    const float2* __restrict__ ce)
{
    const float* qb = rbuf + fb;

    // edge columns for rows rm, r0..r0+RPT-1, rN + boundary-row centers (LDS)
    float2 L[RPT+2], R[RPT+2];
    const float* p0 = qb + RS*rm;
    const float* pN = qb + RS*rN;
    L[0] = *(const float2*)(p0 - 2);  R[0] = *(const float2*)(p0 + 4);
    #pragma unroll
    for (int j = 0; j < RPT; ++j) {
        const float* pr = qb + RS*(r0 + j);
        L[j+1] = *(const float2*)(pr - 2);
        R[j+1] = *(const float2*)(pr + 4);
    }
    L[RPT+1] = *(const float2*)(pN - 2);  R[RPT+1] = *(const float2*)(pN + 4);
    float4 Mb0 = *(const float4*)(p0);
    float4 MbN = *(const float4*)(pN);

    // horizontal [1,2,1] sums
    float2 hu[RPT+2], hv[RPT+2];
    hu[0] = make_float2(fmaf(2.f,Mb0.x,L[0].x)+Mb0.z, fmaf(2.f,Mb0.z,Mb0.x)+R[0].x);
    hv[0] = make_float2(fmaf(2.f,Mb0.y,L[0].y)+Mb0.w, fmaf(2.f,Mb0.w,Mb0.y)+R[0].y);
    #pragma unroll
    for (int j = 0; j < RPT; ++j) {
        float4 Mc = Mreg[j];
        hu[j+1] = make_float2(fmaf(2.f,Mc.x,L[j+1].x)+Mc.z, fmaf(2.f,Mc.z,Mc.x)+R[j+1].x);
        hv[j+1] = make_float2(fmaf(2.f,Mc.y,L[j+1].y)+Mc.w, fmaf(2.f,Mc.w,Mc.y)+R[j+1].y);
    }
    hu[RPT+1] = make_float2(fmaf(2.f,MbN.x,L[RPT+1].x)+MbN.z, fmaf(2.f,MbN.z,MbN.x)+R[RPT+1].x);
    hv[RPT+1] = make_float2(fmaf(2.f,MbN.y,L[RPT+1].y)+MbN.w, fmaf(2.f,MbN.w,MbN.y)+R[RPT+1].y);

    // vertical combine + coupled update + write + register carry
    #pragma unroll
    for (int j = 0; j < RPT; ++j) {
        float4 Mc = Mreg[j];
        float tux = fmaf(-4.f, Mc.x, fmaf(2.f, hu[j+1].x, hu[j].x) + hu[j+2].x);
        float tuy = fmaf(-4.f, Mc.z, fmaf(2.f, hu[j+1].y, hu[j].y) + hu[j+2].y);
        float tvx = fmaf(-4.f, Mc.y, fmaf(2.f, hv[j+1].x, hv[j].x) + hv[j+2].x);
        float tvy = fmaf(-4.f, Mc.w, fmaf(2.f, hv[j+1].y, hv[j].y) + hv[j+2].y);
        float2 un, vn;
        un.x = fmaf(ca[j].x, tux, -fmaf(cb[j].x, tvx, cc[j].x));
        un.y = fmaf(ca[j].y, tuy, -fmaf(cb[j].y, tvy, cc[j].y));
        vn.x = fmaf(cd[j].x, tvx, -fmaf(cb[j].x, tux, ce[j].x));
        vn.y = fmaf(cd[j].y, tvy, -fmaf(cb[j].y, tuy, ce[j].y));
        float4 nv = make_float4(un.x, vn.x, un.y, vn.y);
        *(float4*)(wbuf + RS*(r0 + j) + fb) = nv;
        Mreg[j] = nv;
    }
}

__global__ __launch_bounds__(NTHR, 2)
void hs_mega(const float* __restrict__ x,     // (8,3,256,256): It, Ix, Iy
             const float* __restrict__ est,   // (8,2,256,256): u0, v0
             float* __restrict__ out,         // (8,2,256,256)
             float* __restrict__ ws)          // rings (double-buffered) + flags
{
    extern __shared__ __align__(16) float smem[];
    float* s0 = smem;
    float* s1 = smem + LBUF;

    const int img = blockIdx.x, cs = blockIdx.y, rb = blockIdx.z;
    const int tid = threadIdx.x;
    const int er0 = rb*TILE_R - TT;
    const int ec0 = cs*TILE_C - TT;
    const int blin = (img*4 + cs)*8 + rb;      // 0..255
    unsigned* flags = (unsigned*)(ws + FLAG_OFS);

    // neighbor block id for the 8 poller threads (same image, 8-neighborhood)
    int nb = -1;
    if (tid < 8) {
        int t = (tid < 4) ? tid : tid + 1;     // skip (0,0)
        int dr = t/3 - 1, dc = t%3 - 1;
        int nrb = rb + dr, ncs = cs + dc;
        if (nrb >= 0 && nrb < 8 && ncs >= 0 && ncs < 4)
            nb = (img*4 + ncs)*8 + nrb;
    }

    // ---- per-thread sweep geometry: 2 adjacent uv-cols x RPT rows ----
    const int cp = tid % NCP;          // 0..47
    const int rg = tid / NCP;          // 0..7
    const int r0 = rg * RPT;
    const int fb = 4 + 4*cp;           // float index of col pair in row 0
    const int rm = (r0 == 0) ? 0 : r0 - 1;             // clamp: feeds d=0 ring only
    const int rN = (r0 + RPT > ER-1) ? ER-1 : r0+RPT;  // clamp: feeds d=0 ring only

    // ---- per-pixel update coefficients, computed ONCE, live in registers ----
    // out-of-image px get all-zero coeffs -> computed value stays 0 every step,
    // exactly matching the reference's SAME zero padding.
    float2 ca[RPT], cb[RPT], cc[RPT], cd[RPT], ce[RPT];
    {
        const float* __restrict__ xit = x + img*3*PLANE;
        const float* __restrict__ xix = xit + PLANE;
        const float* __restrict__ xiy = xix + PLANE;
        #pragma unroll
        for (int i = 0; i < RPT; ++i) {
            int gr = er0 + r0 + i;
            #pragma unroll
            for (int j = 0; j < 2; ++j) {
                int gc = ec0 + 2*cp + j;
                float A=0.f, B=0.f, C=0.f, D=0.f, E=0.f;
                if (gr >= 0 && gr < HH && gc >= 0 && gc < WW) {
                    int q = gr*WW + gc;
                    float it = xit[q], ix = xix[q], iy = xiy[q];
                    float rd = 1.0f / (1.0f + ix*ix + iy*iy);
                    const float s12 = 1.0f/12.0f;
                    A = (1.0f - ix*ix*rd) * s12;
                    B = (ix*iy*rd) * s12;
                    C = ix*it*rd;
                    D = (1.0f - iy*iy*rd) * s12;
                    E = iy*it*rd;
                }
                if (j == 0) { ca[i].x=A; cb[i].x=B; cc[i].x=C; cd[i].x=D; ce[i].x=E; }
                else        { ca[i].y=A; cb[i].y=B; cc[i].y=C; cd[i].y=D; ce[i].y=E; }
            }
        }
    }

    // ---- initial full ext-tile stage from est (interleave on the fly) ----
    {
        const float* __restrict__ eu = est + img*2*PLANE;
        const float* __restrict__ ev = eu + PLANE;
        for (int k = tid; k < ER*NCP; k += NTHR) {           // 3072 pairs
            int r = k / NCP, c = k - r*NCP;
            int gr = er0 + r, gc = ec0 + 2*c;
            float2 uu = make_float2(0.f,0.f), vv = make_float2(0.f,0.f);
            if (gr >= 0 && gr < HH && gc >= 0 && gc < WW) {  // gc even -> pair in-bounds
                uu = *(const float2*)(eu + gr*WW + gc);
                vv = *(const float2*)(ev + gr*WW + gc);
            }
            *(float4*)(s0 + 4 + RS*r + 4*c) = make_float4(uu.x, vv.x, uu.y, vv.y);
        }
    }
    __syncthreads();

    // own-row center values, carried in registers; refreshed after each restage
    float4 Mreg[RPT];
    #pragma unroll
    for (int j = 0; j < RPT; ++j)
        Mreg[j] = *(const float4*)(s0 + RS*(r0 + j) + fb);

    for (int p = 0; p < 7; ++p) {
        const int ndbl = (p < 6) ? (TT/2) : 2;   // 16 or 4 steps, as double-steps

        // ---- steps in LDS (ping-pong), 1 barrier each, result lands in s0 ----
        for (int q = 0; q < ndbl; ++q) {
            hs_step(s0, s1, fb, rm, r0, rN, Mreg, ca, cb, cc, cd, ce);
            __syncthreads();
            hs_step(s1, s0, fb, rm, r0, rN, Mreg, ca, cb, cc, cd, ce);
            __syncthreads();
        }

        if (p < 6) {
            float* ring = ws + (unsigned)(p & 1) * RING_OFS + img*RIMG;

            // ---- write FULL inner tile to ring (all px within 16 of tile edge) ----
            for (int k = tid; k < TILE_R*(TILE_C/2); k += NTHR) {   // 1024 pairs
                int r = k >> 5, c2 = k & 31;
                const float* sp = s0 + 4 + RS*(r + TT) + 4*(c2 + TT/2);
                float* gp = ring + ((rb*TILE_R + r)*(WW/2) + cs*(TILE_C/2) + c2)*4;
                __hip_atomic_store((ull*)gp,     *(const ull*)sp,       __ATOMIC_RELAXED, __HIP_MEMORY_SCOPE_AGENT);
                __hip_atomic_store((ull*)gp + 1, *(const ull*)(sp + 2), __ATOMIC_RELAXED, __HIP_MEMORY_SCOPE_AGENT);
            }
            asm volatile("s_waitcnt vmcnt(0)" ::: "memory");   // per-wave drain of ring stores
            __syncthreads();
            if (tid == 0)
                __hip_atomic_store(&flags[p*NBLK + blin], 0x5eed0100u + (unsigned)p,
                                   __ATOMIC_RELAXED, __HIP_MEMORY_SCOPE_AGENT);
            asm volatile("" ::: "memory");
            if (tid < 8 && nb >= 0) {
                const unsigned tgt = 0x5eed0100u + (unsigned)p;
                while (__hip_atomic_load(&flags[p*NBLK + nb],
                                         __ATOMIC_RELAXED, __HIP_MEMORY_SCOPE_AGENT) != tgt)
                    __builtin_amdgcn_s_sleep(1);
            }
            __syncthreads();

            // ---- restage depth-16 ext halo ring from neighbors ----
            // rows 0..15 + 48..63 full width (2x768 pairs) + rows 16..47 side pairs (512)
            for (int k = tid; k < 2048; k += NTHR) {
                int m = k; int r, c2;
                if (m < 768)       { r = m / NCP;              c2 = m - (m/NCP)*NCP; }
                else if (m < 1536) { int mm = m-768; r = 48 + mm/NCP; c2 = mm - (mm/NCP)*NCP; }
                else { int mm = m - 1536; r = 16 + (mm >> 4); int t = mm & 15; c2 = (t < 8) ? t : 32 + t; }
                int gr = er0 + r, gc2 = cs*(TILE_C/2) - TT/2 + c2;
                ull v0 = 0, v1 = 0;
                if (gr >= 0 && gr < HH && gc2 >= 0 && gc2 < WW/2) {
                    const float* gp = ring + (gr*(WW/2) + gc2)*4;
                    v0 = __hip_atomic_load((const ull*)gp,     __ATOMIC_RELAXED, __HIP_MEMORY_SCOPE_AGENT);
                    v1 = __hip_atomic_load((const ull*)gp + 1, __ATOMIC_RELAXED, __HIP_MEMORY_SCOPE_AGENT);
                }
                float* sp = s0 + 4 + RS*r + 4*c2;
                *(ull*)sp = v0;
                *(ull*)(sp + 2) = v1;
            }
            __syncthreads();

            // refresh carried centers (restage rewrote halo regions of s0)
            #pragma unroll
            for (int j = 0; j < RPT; ++j)
                Mreg[j] = *(const float4*)(s0 + RS*(r0 + j) + fb);
        }
    }

    // ---- final: de-interleave inner tile to planar out ----
    {
        float* ou = out + img*2*PLANE;
        float* ov = ou + PLANE;
        for (int k = tid; k < TILE_R*(TILE_C/2); k += NTHR) {   // 1024 pairs
            int r = k >> 5, c2 = k & 31;
            float4 V = *(const float4*)(s0 + 4 + RS*(r + TT) + 4*(c2 + TT/2));
            int q = (rb*TILE_R + r)*WW + cs*TILE_C + 2*c2;
            *(float2*)(ou + q) = make_float2(V.x, V.z);
            *(float2*)(ov + q) = make_float2(V.y, V.w);
        }
    }
}

extern "C" void kernel_launch(void* const* d_in, const int* in_sizes, int n_in,
                              void* d_out, int out_size, void* d_ws, size_t ws_size,
                              hipStream_t stream) {
    const float* x   = (const float*)d_in[0];   // (8,3,256,256) fp32
    const float* est = (const float*)d_in[1];   // (8,2,256,256) fp32
    float* out = (float*)d_out;
    float* ws  = (float*)d_ws;                  // ring slot0 @0, slot1 @8MB, flags @16MB
                                                // flags 0xAA-poisoned each launch: != MAGIC, no reset needed

    // 98.4 KB dynamic LDS per block (> 64 KB static limit, <= 160 KB/CU).
    // Host-side attribute set; not a stream op -> graph-capture safe.
    hipFuncSetAttribute((const void*)hs_mega,
                        hipFuncAttributeMaxDynamicSharedMemorySize, SMEM_BYTES);

    dim3 grid(8, WW/TILE_C, HH/TILE_R);         // 256 blocks, all co-resident (1/CU by LDS)
    dim3 blk(NTHR);
    hs_mega<<<grid, blk, SMEM_BYTES, stream>>>(x, est, out, ws);
}